// Round 10
// baseline (60.936 us; speedup 1.0000x reference)
//
#include <hip/hip_runtime.h>

// Problem constants (hardcoded in the reference)
#define NPIX 65536   // 256*256 = 2^16
#define KK   361     // 19*19
#define LSZ  19
#define HWD  256
#define CHUNK 64     // q per block
#define SUBT  16     // q per sub-tile (4 sub-tiles, 1 barrier each)
#define GPART (NPIX / CHUNK)      // 1024 blocks
#define NSLOT 8      // partial slots per row (window <= 7, one 64B line)
#define NS2  16      // s-strips for S1
#define SPS2 23      // s-rows per strip (last strip: 361 - 15*23 = 16)
#define DTC  82      // in2 LDS tile cols = CHUNK-1 + LSZ

// reflect-pad index (pad=9, size 256, mode="reflect"); arg is (coord + offset)
__device__ __forceinline__ int refl(int v) {
    v -= 9;
    v = v < 0 ? -v : v;
    v = v > 255 ? 510 - v : v;
    return v;
}

// ---------------------------------------------------------------------------
// S1a: partial column sums, contiguous float4 reads (the only cold HBM pass).
// ---------------------------------------------------------------------------
__global__ __launch_bounds__(256) void k_s1a(const float4* __restrict__ ker4,
                                             float4* __restrict__ part4) {
    const int p4 = blockIdx.x * 256 + threadIdx.x;   // [0, 16384)
    const int strip = blockIdx.y;
    const int s0 = strip * SPS2;
    const int n = (strip == NS2 - 1) ? (KK - s0) : SPS2;
    const float4* kp = ker4 + (size_t)s0 * (NPIX / 4) + p4;
    float4 acc = {0.f, 0.f, 0.f, 0.f};
#pragma unroll 8
    for (int s = 0; s < n; ++s) {
        float4 v = kp[(size_t)s * (NPIX / 4)];
        acc.x += v.x; acc.y += v.y; acc.z += v.z; acc.w += v.w;
    }
    part4[(size_t)strip * (NPIX / 4) + p4] = acc;
}

// S1b: rcpS1[p] = 1 / sum_strips
__global__ __launch_bounds__(256) void k_s1b(const float4* __restrict__ part4,
                                             float4* __restrict__ rcp4) {
    const int i = blockIdx.x * 256 + threadIdx.x;    // [0, 16384)
    float4 a = {0.f, 0.f, 0.f, 0.f};
#pragma unroll
    for (int s = 0; s < NS2; ++s) {
        float4 v = part4[(size_t)s * (NPIX / 4) + i];
        a.x += v.x; a.y += v.y; a.z += v.z; a.w += v.w;
    }
    rcp4[i] = float4{1.0f / a.x, 1.0f / a.y, 1.0f / a.z, 1.0f / a.w};
}

// ---------------------------------------------------------------------------
// k_part (cache-direct): no ker LDS tile. Block = 64 consecutive q, processed
// as 4 sub-tiles of 16 rows:
//   rowsum sub-tile k (coalesced global reads, shuffle-reduce) -> rcpS2s
//   __syncthreads()                                (1 barrier per sub-tile)
//   accum  sub-tile k: v = ker[m]*rcpS1[m&0xFFFF]*rcpS2s[off]; lane-contiguous
//          global reads hit L2 (sub-tile footprint ~3.7 MB/XCD <= 4 MB L2).
// LDS: dt patch (19x82) + rcpS2s[64] only. Chunk-carry accumulator with one
// snapshot at the row boundary (<=1 per 64 < 361). Stores: <=2 float2/lane.
// XCD swizzle: co-writer chunks of a partial line stay on one XCD.
// ---------------------------------------------------------------------------
__global__ __launch_bounds__(384) void k_part(const float* __restrict__ ker,
                                              const float* __restrict__ rcpS1,
                                              const float* __restrict__ in2,
                                              float2* __restrict__ partial) {
    __shared__ float dt[LSZ * DTC];      // 6,232 B
    __shared__ float rcpS2s[CHUNK];
    const int tid = threadIdx.x;
    const int lb  = ((blockIdx.x & 7) << 7) | (blockIdx.x >> 3);  // 1024 = 8*128
    const int q0  = lb * CHUNK;

    // stage reflected in2 patch (runs under sub-tile 0's rowsum, before bar 0)
    {
        const int y0 = q0 >> 8, x0 = q0 & 255;
        for (int i = tid; i < LSZ * DTC; i += 384) {
            int a = i / DTC, c = i - a * DTC;
            dt[i] = in2[refl(y0 + a) * HWD + refl(x0 + c)];
        }
    }

    // per-lane chunk-carry state
    const int t  = tid;
    const int j0 = t * NPIX + q0;             // < 2^25
    const int r0 = j0 / KK;
    const int jm = j0 - r0 * KK;
    const int d0 = (jm == 0) ? CHUNK : (KK - jm);
    const int split = d0 < CHUNK ? d0 : CHUNK;     // [1, 64]
    const int a = t / LSZ, b = t - LSZ * a;
    const int dbase = a * DTC + b;
    float ad = 0.f, as = 0.f, sd = 0.f, ss = 0.f;

    const int wave = tid >> 6, lane = tid & 63;

    for (int k = 0; k < 4; ++k) {
        // rowsum for rows [16k, 16k+16): wave w takes rows 16k+w, +6, +12
        for (int o = SUBT * k + wave; o < SUBT * (k + 1); o += 6) {
            const int base = (q0 + o) * KK;
            float acc = 0.f;
#pragma unroll
            for (int e = lane; e < KK; e += 64)
                acc += ker[base + e] * rcpS1[(base + e) & (NPIX - 1)];
            for (int m = 1; m < 64; m <<= 1) acc += __shfl_xor(acc, m);
            if (lane == 0) rcpS2s[o] = 1.0f / acc;
        }
        __syncthreads();   // rcpS2s[16k..) ready (and dt, for k=0)
        if (t < KK) {
#pragma unroll
            for (int oo = 0; oo < SUBT; ++oo) {
                const int off = SUBT * k + oo;
                if (off == split) { sd = ad; ss = as; }   // snapshot at boundary
                const int m = (q0 + off) * KK + t;        // lane-contiguous
                float v = ker[m] * rcpS1[m & (NPIX - 1)] * rcpS2s[off];
                float d = dt[dbase + off];
                ad += d * v;
                as += v;
            }
        }
        // no barrier here: next rowsum writes rcpS2s[16(k+1)..), disjoint
    }

    if (t < KK) {
        const int slot = lb & (NSLOT - 1);
        if (split == CHUNK) {
            partial[(size_t)r0 * NSLOT + slot] = float2{ad, as};
        } else {
            partial[(size_t)r0 * NSLOT + slot] = float2{sd, ss};
            partial[(size_t)(r0 + 1) * NSLOT + slot] = float2{ad - sd, as - ss};
        }
    }
}

// ---------------------------------------------------------------------------
// k_out2: sum the valid slot window for row r (no zero-init needed).
// Chunks touching row r: [qs>>6 .. ql>>6] (mod GPART), <= 7 wide;
// slots = chunk & 7, distinct. Whole window lives in ONE 64B line.
// ---------------------------------------------------------------------------
__global__ __launch_bounds__(256) void k_out2(const float2* __restrict__ partial,
                                              float* __restrict__ out) {
    const int r = blockIdx.x * 256 + threadIdx.x;
    const int j0 = r * KK;
    const int qs = j0 & (NPIX - 1);
    const int ql = (j0 + KK - 1) & (NPIX - 1);
    const int first = qs >> 6;
    const int last  = ql >> 6;
    const int cnt = ((last - first) & (GPART - 1)) + 1;
    const float2* p = partial + (size_t)r * NSLOT;
    float dot = 0.f, sum = 0.f;
    for (int i = 0; i < cnt; ++i) {
        float2 v = p[(first + i) & (NSLOT - 1)];
        dot += v.x; sum += v.y;
    }
    out[r] = dot / sum;
}

// ---------------------------------------------------------------------------
// Minimal fallback path (tiny ws): direct strided gathers.
// ---------------------------------------------------------------------------
__global__ __launch_bounds__(256) void k_s1(const float* __restrict__ ker,
                                            float* __restrict__ rcpS1) {
    int p = blockIdx.x * blockDim.x + threadIdx.x;
    const float* kp = ker + p;
    float a = 0.f;
    for (int s = 0; s < KK; ++s) a += kp[(size_t)s * NPIX];
    rcpS1[p] = 1.0f / a;
}

__global__ __launch_bounds__(256) void k_s2_fallback(const float* __restrict__ ker,
                                                     const float* __restrict__ rcpS1,
                                                     float* __restrict__ rcpS2) {
    int lane = threadIdx.x & 63;
    int q = blockIdx.x * 4 + (threadIdx.x >> 6);
    int base = q * KK;
    float acc = 0.f;
    for (int t = lane; t < KK; t += 64)
        acc += ker[base + t] * rcpS1[(base + t) & (NPIX - 1)];
    for (int m = 1; m < 64; m <<= 1) acc += __shfl_xor(acc, m);
    if (lane == 0) rcpS2[q] = 1.0f / acc;
}

__global__ __launch_bounds__(256) void k_out_fallback(const float* __restrict__ ker,
                                                      const float* __restrict__ rcpS1,
                                                      const float* __restrict__ rcpS2,
                                                      const float* __restrict__ in2,
                                                      float* __restrict__ out) {
    int lane = threadIdx.x & 63;
    int r = blockIdx.x * 4 + (threadIdx.x >> 6);
    float vsum = 0.f, vdot = 0.f;
    for (int u = lane; u < KK; u += 64) {
        int jj = r * KK + u;
        int t  = jj >> 16;
        int q  = jj & (NPIX - 1);
        int m  = q * KK + t;
        float v = ker[m] * rcpS1[m & (NPIX - 1)] * rcpS2[q];
        int y = q >> 8, x = q & 255;
        int a = t / LSZ, b = t - a * LSZ;
        float d = in2[refl(y + a) * HWD + refl(x + b)];
        vsum += v;
        vdot += d * v;
    }
    for (int mm = 1; mm < 64; mm <<= 1) {
        vsum += __shfl_xor(vsum, mm);
        vdot += __shfl_xor(vdot, mm);
    }
    if (lane == 0) out[r] = vdot / vsum;
}

extern "C" void kernel_launch(void* const* d_in, const int* in_sizes, int n_in,
                              void* d_out, int out_size, void* d_ws, size_t ws_size,
                              hipStream_t stream) {
    const float* inp = (const float*)d_in[0];   // (1,3,256,256)
    const float* ker = (const float*)d_in[1];   // (19,19,256,256)
    float* out = (float*)d_out;                 // (1,1,256,256)
    const float* in2 = inp + 2 * NPIX;          // channel 2

    float*  rcpS1   = (float*)d_ws;                           // NPIX
    float*  s1part  = rcpS1 + NPIX;                           // NS2*NPIX
    float2* partial = (float2*)(s1part + (size_t)NS2 * NPIX); // NPIX*NSLOT float2

    const size_t needed = ((size_t)NPIX * (1 + NS2) +
                           (size_t)NPIX * NSLOT * 2) * sizeof(float);  // ~8.25 MB

    if (ws_size >= needed) {
        dim3 g1(NPIX / 4 / 256, NS2);   // (64, 16)
        k_s1a<<<g1, 256, 0, stream>>>((const float4*)ker, (float4*)s1part);
        k_s1b<<<NPIX / 4 / 256, 256, 0, stream>>>((const float4*)s1part, (float4*)rcpS1);
        k_part<<<GPART, 384, 0, stream>>>(ker, rcpS1, in2, partial);
        k_out2<<<NPIX / 256, 256, 0, stream>>>(partial, out);
    } else {
        float* rcpS2 = rcpS1 + NPIX;   // fallback needs only 512 KB
        k_s1<<<NPIX / 256, 256, 0, stream>>>(ker, rcpS1);
        k_s2_fallback<<<NPIX / 4, 256, 0, stream>>>(ker, rcpS1, rcpS2);
        k_out_fallback<<<NPIX / 4, 256, 0, stream>>>(ker, rcpS1, rcpS2, in2, out);
    }
}

// Round 11
// 54.241 us; speedup vs baseline: 1.1234x; 1.1234x over previous
//
#include <hip/hip_runtime.h>

// Problem constants (hardcoded in the reference)
#define NPIX 65536   // 256*256 = 2^16
#define KK   361     // 19*19
#define LSZ  19
#define HWD  256
#define QB   8       // q-rows per sub-tile
#define NT   8       // sub-tiles per chunk
#define CHUNK 64     // q per block = QB*NT
#define GPART (NPIX / CHUNK)      // 1024 blocks
#define NSLOT 8      // partial slots per row (window <= 7, one 64B line)
#define NS2  16      // s-strips for S1
#define SPS2 23      // s-rows per strip (last strip: 361 - 15*23 = 16)
#define DTC  82      // in2 LDS tile cols = CHUNK-1 + LSZ

// reflect-pad index (pad=9, size 256, mode="reflect"); arg is (coord + offset)
__device__ __forceinline__ int refl(int v) {
    v -= 9;
    v = v < 0 ? -v : v;
    v = v > 255 ? 510 - v : v;
    return v;
}

// ---------------------------------------------------------------------------
// S1a: partial column sums, contiguous float4 reads (the only cold HBM pass).
// ---------------------------------------------------------------------------
__global__ __launch_bounds__(256) void k_s1a(const float4* __restrict__ ker4,
                                             float4* __restrict__ part4) {
    const int p4 = blockIdx.x * 256 + threadIdx.x;   // [0, 16384)
    const int strip = blockIdx.y;
    const int s0 = strip * SPS2;
    const int n = (strip == NS2 - 1) ? (KK - s0) : SPS2;
    const float4* kp = ker4 + (size_t)s0 * (NPIX / 4) + p4;
    float4 acc = {0.f, 0.f, 0.f, 0.f};
#pragma unroll 8
    for (int s = 0; s < n; ++s) {
        float4 v = kp[(size_t)s * (NPIX / 4)];
        acc.x += v.x; acc.y += v.y; acc.z += v.z; acc.w += v.w;
    }
    part4[(size_t)strip * (NPIX / 4) + p4] = acc;
}

// S1b: rcpS1[p] = 1 / sum_strips
__global__ __launch_bounds__(256) void k_s1b(const float4* __restrict__ part4,
                                             float4* __restrict__ rcp4) {
    const int i = blockIdx.x * 256 + threadIdx.x;    // [0, 16384)
    float4 a = {0.f, 0.f, 0.f, 0.f};
#pragma unroll
    for (int s = 0; s < NS2; ++s) {
        float4 v = part4[(size_t)s * (NPIX / 4) + i];
        a.x += v.x; a.y += v.y; a.z += v.z; a.w += v.w;
    }
    rcp4[i] = float4{1.0f / a.x, 1.0f / a.y, 1.0f / a.z, 1.0f / a.w};
}

// ---------------------------------------------------------------------------
// k_part (pipelined, double-buffered): block = 64 consecutive q, 8 sub-tiles
// of 8 rows. Per iteration k, between single barriers, THREE independent
// streams overlap inside every wave's instruction stream:
//   stage(k+1): ker -> buf[(k+1)&1], scaled by rcpS1   [VMEM + DS-write]
//   rowsum(k+1): global coalesced reads -> rcpS2s      [VMEM + shfl]
//                (same lines stage streams -> L1-hot; same products/order
//                 as the old LDS rowsum -> bit-identical)
//   accum(k):  buf[k&1] + dt + rcpS2s                  [DS-read + VALU]
// Chunk-carry accumulator with one snapshot at the <=1 row boundary per 64.
// LDS 29.6 KB -> 5 blocks/CU possible; grid needs 4 -> single generation.
// XCD swizzle keeps co-writers of each partial 64B line on one XCD.
// ---------------------------------------------------------------------------
__global__ __launch_bounds__(384, 4) void k_part(const float* __restrict__ ker,
                                                 const float* __restrict__ rcpS1,
                                                 const float* __restrict__ in2,
                                                 float2* __restrict__ partial) {
    __shared__ float buf[2][QB * KK];    // 2 x 11,552 B
    __shared__ float dt[LSZ * DTC];      // 6,232 B
    __shared__ float rcpS2s[CHUNK];
    const int tid = threadIdx.x;
    const int lb  = ((blockIdx.x & 7) << 7) | (blockIdx.x >> 3);  // 1024 = 8*128
    const int q0  = lb * CHUNK;
    const int wave = tid >> 6, lane = tid & 63;

    // stage reflected in2 patch
    {
        const int y0 = q0 >> 8, x0 = q0 & 255;
        for (int i = tid; i < LSZ * DTC; i += 384) {
            int a = i / DTC, c = i - a * DTC;
            dt[i] = in2[refl(y0 + a) * HWD + refl(x0 + c)];
        }
    }
    // prologue: stage(0) -> buf[0], rowsum(0)
    {
        const int base0 = q0 * KK;
        const float4* k4 = (const float4*)(ker + base0);
        for (int i = tid; i < (QB * KK) / 4; i += 384) {
            float4 v = k4[i];
            int m = base0 + i * 4;
            const float4 s = *(const float4*)(rcpS1 + (m & (NPIX - 1)));
            v.x *= s.x; v.y *= s.y; v.z *= s.z; v.w *= s.w;
            *(float4*)(&buf[0][i * 4]) = v;
        }
        for (int o = wave; o < QB; o += 6) {
            const int rb = (q0 + o) * KK;
            float acc = 0.f;
#pragma unroll
            for (int e = lane; e < KK; e += 64)
                acc += ker[rb + e] * rcpS1[(rb + e) & (NPIX - 1)];
            for (int m = 1; m < 64; m <<= 1) acc += __shfl_xor(acc, m);
            if (lane == 0) rcpS2s[o] = 1.0f / acc;
        }
    }
    __syncthreads();

    // per-lane chunk-carry state
    const int t  = tid;
    const int j0 = t * NPIX + q0;             // < 2^25
    const int r0 = j0 / KK;
    const int jm = j0 - r0 * KK;
    const int d0 = (jm == 0) ? CHUNK : (KK - jm);
    const int split = d0 < CHUNK ? d0 : CHUNK;     // [1, 64]
    const int a = t / LSZ, b = t - LSZ * a;
    const int dbase = a * DTC + b;
    float ad = 0.f, as = 0.f, sd = 0.f, ss = 0.f;

    for (int k = 0; k < NT; ++k) {
        if (k + 1 < NT) {
            // stage(k+1) into the other buffer
            const int basek = (q0 + (k + 1) * QB) * KK;
            const float4* k4 = (const float4*)(ker + basek);
            float* bufn = buf[(k + 1) & 1];
            for (int i = tid; i < (QB * KK) / 4; i += 384) {
                float4 v = k4[i];
                int m = basek + i * 4;
                const float4 s = *(const float4*)(rcpS1 + (m & (NPIX - 1)));
                v.x *= s.x; v.y *= s.y; v.z *= s.z; v.w *= s.w;
                *(float4*)(&bufn[i * 4]) = v;
            }
            // rowsum(k+1) from global (L1-hot: stage streams the same lines)
            for (int o = QB * (k + 1) + wave; o < QB * (k + 2); o += 6) {
                const int rb = (q0 + o) * KK;
                float acc = 0.f;
#pragma unroll
                for (int e = lane; e < KK; e += 64)
                    acc += ker[rb + e] * rcpS1[(rb + e) & (NPIX - 1)];
                for (int m = 1; m < 64; m <<= 1) acc += __shfl_xor(acc, m);
                if (lane == 0) rcpS2s[o] = 1.0f / acc;
            }
        }
        // accum(k) from buf[k&1]
        if (t < KK) {
            const float* bc = buf[k & 1];
#pragma unroll
            for (int oo = 0; oo < QB; ++oo) {
                const int off = QB * k + oo;
                if (off == split) { sd = ad; ss = as; }   // snapshot at boundary
                float v = bc[oo * KK + t] * rcpS2s[off];
                float d = dt[dbase + off];
                ad += d * v;
                as += v;
            }
        }
        __syncthreads();
    }

    if (t < KK) {
        const int slot = lb & (NSLOT - 1);
        if (split == CHUNK) {
            partial[(size_t)r0 * NSLOT + slot] = float2{ad, as};
        } else {
            partial[(size_t)r0 * NSLOT + slot] = float2{sd, ss};
            partial[(size_t)(r0 + 1) * NSLOT + slot] = float2{ad - sd, as - ss};
        }
    }
}

// ---------------------------------------------------------------------------
// k_out2: sum the valid slot window for row r (no zero-init needed).
// Chunks touching row r: [qs>>6 .. ql>>6] (mod GPART), <= 7 wide;
// slots = chunk & 7, distinct. Whole window lives in ONE 64B line.
// ---------------------------------------------------------------------------
__global__ __launch_bounds__(256) void k_out2(const float2* __restrict__ partial,
                                              float* __restrict__ out) {
    const int r = blockIdx.x * 256 + threadIdx.x;
    const int j0 = r * KK;
    const int qs = j0 & (NPIX - 1);
    const int ql = (j0 + KK - 1) & (NPIX - 1);
    const int first = qs >> 6;
    const int last  = ql >> 6;
    const int cnt = ((last - first) & (GPART - 1)) + 1;
    const float2* p = partial + (size_t)r * NSLOT;
    float dot = 0.f, sum = 0.f;
    for (int i = 0; i < cnt; ++i) {
        float2 v = p[(first + i) & (NSLOT - 1)];
        dot += v.x; sum += v.y;
    }
    out[r] = dot / sum;
}

// ---------------------------------------------------------------------------
// Minimal fallback path (tiny ws): direct strided gathers.
// ---------------------------------------------------------------------------
__global__ __launch_bounds__(256) void k_s1(const float* __restrict__ ker,
                                            float* __restrict__ rcpS1) {
    int p = blockIdx.x * blockDim.x + threadIdx.x;
    const float* kp = ker + p;
    float a = 0.f;
    for (int s = 0; s < KK; ++s) a += kp[(size_t)s * NPIX];
    rcpS1[p] = 1.0f / a;
}

__global__ __launch_bounds__(256) void k_s2_fallback(const float* __restrict__ ker,
                                                     const float* __restrict__ rcpS1,
                                                     float* __restrict__ rcpS2) {
    int lane = threadIdx.x & 63;
    int q = blockIdx.x * 4 + (threadIdx.x >> 6);
    int base = q * KK;
    float acc = 0.f;
    for (int t = lane; t < KK; t += 64)
        acc += ker[base + t] * rcpS1[(base + t) & (NPIX - 1)];
    for (int m = 1; m < 64; m <<= 1) acc += __shfl_xor(acc, m);
    if (lane == 0) rcpS2[q] = 1.0f / acc;
}

__global__ __launch_bounds__(256) void k_out_fallback(const float* __restrict__ ker,
                                                      const float* __restrict__ rcpS1,
                                                      const float* __restrict__ rcpS2,
                                                      const float* __restrict__ in2,
                                                      float* __restrict__ out) {
    int lane = threadIdx.x & 63;
    int r = blockIdx.x * 4 + (threadIdx.x >> 6);
    float vsum = 0.f, vdot = 0.f;
    for (int u = lane; u < KK; u += 64) {
        int jj = r * KK + u;
        int t  = jj >> 16;
        int q  = jj & (NPIX - 1);
        int m  = q * KK + t;
        float v = ker[m] * rcpS1[m & (NPIX - 1)] * rcpS2[q];
        int y = q >> 8, x = q & 255;
        int a = t / LSZ, b = t - a * LSZ;
        float d = in2[refl(y + a) * HWD + refl(x + b)];
        vsum += v;
        vdot += d * v;
    }
    for (int mm = 1; mm < 64; mm <<= 1) {
        vsum += __shfl_xor(vsum, mm);
        vdot += __shfl_xor(vdot, mm);
    }
    if (lane == 0) out[r] = vdot / vsum;
}

extern "C" void kernel_launch(void* const* d_in, const int* in_sizes, int n_in,
                              void* d_out, int out_size, void* d_ws, size_t ws_size,
                              hipStream_t stream) {
    const float* inp = (const float*)d_in[0];   // (1,3,256,256)
    const float* ker = (const float*)d_in[1];   // (19,19,256,256)
    float* out = (float*)d_out;                 // (1,1,256,256)
    const float* in2 = inp + 2 * NPIX;          // channel 2

    float*  rcpS1   = (float*)d_ws;                           // NPIX
    float*  s1part  = rcpS1 + NPIX;                           // NS2*NPIX
    float2* partial = (float2*)(s1part + (size_t)NS2 * NPIX); // NPIX*NSLOT float2

    const size_t needed = ((size_t)NPIX * (1 + NS2) +
                           (size_t)NPIX * NSLOT * 2) * sizeof(float);  // ~8.25 MB

    if (ws_size >= needed) {
        dim3 g1(NPIX / 4 / 256, NS2);   // (64, 16)
        k_s1a<<<g1, 256, 0, stream>>>((const float4*)ker, (float4*)s1part);
        k_s1b<<<NPIX / 4 / 256, 256, 0, stream>>>((const float4*)s1part, (float4*)rcpS1);
        k_part<<<GPART, 384, 0, stream>>>(ker, rcpS1, in2, partial);
        k_out2<<<NPIX / 256, 256, 0, stream>>>(partial, out);
    } else {
        float* rcpS2 = rcpS1 + NPIX;   // fallback needs only 512 KB
        k_s1<<<NPIX / 256, 256, 0, stream>>>(ker, rcpS1);
        k_s2_fallback<<<NPIX / 4, 256, 0, stream>>>(ker, rcpS1, rcpS2);
        k_out_fallback<<<NPIX / 4, 256, 0, stream>>>(ker, rcpS1, rcpS2, in2, out);
    }
}